// Round 6
// baseline (144.087 us; speedup 1.0000x reference)
//
#include <hip/hip_runtime.h>

#define NIMG 4
#define NCLS 19
#define CCH  32
#define LH   128
#define LW   128
#define HH   512
#define WW   512
#define HWQ  (LH*LW)    // 16384
#define HWP  (HH*WW)    // 262144

#define TR 8
#define TC 16
#define NTILE 128        // field-role blocks per image (16x8 tiles)
#define HALO_R 36
#define HALO_C 68
#define NHALO (HALO_R*HALO_C)   // 2448
#define QB2 256          // quad-role blocks per image (row x channel-half)
#define ASTR 20          // A row stride: [cell][k], 16B-aligned rows

// union LDS (floats): field: A[128*20]=2560 | cnt[20] | red[4*608]=2432
//                     quad : acc[4*20]=80 (reuses start)
#define L_A    0
#define L_CNT  2560
#define L_RED  2580
#define LDS_FLOATS 5012         // ~20.0 KB -> 8 blocks/CU (LDS-wise)

// Bilinear taps, jax.image.resize half-pixel convention (128 -> 512).
// edge renormalization == clamping (verified absmax 0.0 in R1-R5)
__device__ __forceinline__ void taps(int v, int lim, int& i0, int& i1, float& f) {
    int r = v & 3;
    int b = (v >> 2) + ((r < 2) ? -1 : 0);
    f = 0.125f + 0.25f * (float)((r + 2) & 3);
    i0 = b < 0 ? 0 : b;
    i1 = (b + 1 > lim) ? lim : (b + 1);
}

__global__ __launch_bounds__(256) void k_main(const float* __restrict__ E,
        const int* __restrict__ lab, float* __restrict__ P_sum,
        float* __restrict__ P_cnt, float* __restrict__ P_S2) {
    __shared__ float lds[LDS_FLOATS];
    const int n = blockIdx.y;
    const int tid = threadIdx.x;
    const int bid = blockIdx.x;

    if (bid % 3 == 0) {
        // ================= field role: A-field + fused contract =============
        const int tile = bid / 3;                // 0..127
        const int ty = tile >> 3, tx = tile & 7;
        const int Y0 = ty * TR, X0 = tx * TC;
        for (int i = tid; i < L_RED; i += 256) lds[i] = 0.f;

        // issue contract's E loads NOW (independent of A; overlap atomic phase)
        const int g = tid >> 5, c = tid & 31;    // g = tile row 0..7
        const float* Erow = E + ((size_t)n * CCH + c) * HWQ + (Y0 + g) * LW + X0;
        const float4 e0 = *(const float4*)(Erow + 0);
        const float4 e1 = *(const float4*)(Erow + 4);
        const float4 e2 = *(const float4*)(Erow + 8);
        const float4 e3 = *(const float4*)(Erow + 12);

        // prefetch halo labels (independent loads, one drain)
        const int* ln = lab + (size_t)n * HWP;
        const int h_lo = Y0 * 4 - 2, w_lo = X0 * 4 - 2;
        int Lv[10];
#pragma unroll
        for (int it = 0; it < 10; it++) {
            int i = it * 256 + tid;
            int hr = i / HALO_C, wc = i - hr * HALO_C;
            int h = h_lo + hr, w = w_lo + wc;
            bool ok = (i < NHALO) & (h >= 0) & (h < HH) & (w >= 0) & (w < WW);
            int hc = h < 0 ? 0 : (h > HH - 1 ? HH - 1 : h);
            int wl = w < 0 ? 0 : (w > WW - 1 ? WW - 1 : w);
            int lv = ln[hc * WW + wl];
            Lv[it] = ok ? lv : -1;
        }
        __syncthreads();
#pragma unroll
        for (int it = 0; it < 10; it++) {
            if (Lv[it] < 0) continue;
            int i = it * 256 + tid;
            int hr = i / HALO_C, wc = i - hr * HALO_C;
            int h = h_lo + hr, w = w_lo + wc;
            int y0, y1, x0, x1; float fy, fx;
            taps(h, LH - 1, y0, y1, fy);
            taps(w, LW - 1, x0, x1, fx);
            int yy[2] = {y0, y1}; float wy[2] = {1.f - fy, fy};
            int xx[2] = {x0, x1}; float wx[2] = {1.f - fx, fx};
            float wtot = 0.f;
#pragma unroll
            for (int a = 0; a < 2; a++) {
#pragma unroll
                for (int b = 0; b < 2; b++) {
                    int ry = yy[a] - Y0, rx = xx[b] - X0;
                    if (ry >= 0 && ry < TR && rx >= 0 && rx < TC) {
                        float w_ = wy[a] * wx[b];
                        atomicAdd(&lds[L_A + (ry * TC + rx) * ASTR + Lv[it]], w_);
                        wtot += w_;
                    }
                }
            }
            if (wtot > 0.f) atomicAdd(&lds[L_CNT + Lv[it]], wtot);
        }
        __syncthreads();

        // contract: thread (g,c); A rows via broadcast ds_read_b128
        float ev[16] = {e0.x, e0.y, e0.z, e0.w, e1.x, e1.y, e1.z, e1.w,
                        e2.x, e2.y, e2.z, e2.w, e3.x, e3.y, e3.z, e3.w};
        float acc[NCLS];
#pragma unroll
        for (int k = 0; k < NCLS; k++) acc[k] = 0.f;
#pragma unroll
        for (int cx = 0; cx < TC; cx++) {
            const float* Ar = &lds[L_A + (g * TC + cx) * ASTR];
            const float4 a0 = *(const float4*)(Ar + 0);
            const float4 a1 = *(const float4*)(Ar + 4);
            const float4 a2 = *(const float4*)(Ar + 8);
            const float4 a3 = *(const float4*)(Ar + 12);
            const float a16 = Ar[16], a17 = Ar[17], a18 = Ar[18];
            const float e = ev[cx];
            acc[0]  = fmaf(a0.x, e, acc[0]);  acc[1]  = fmaf(a0.y, e, acc[1]);
            acc[2]  = fmaf(a0.z, e, acc[2]);  acc[3]  = fmaf(a0.w, e, acc[3]);
            acc[4]  = fmaf(a1.x, e, acc[4]);  acc[5]  = fmaf(a1.y, e, acc[5]);
            acc[6]  = fmaf(a1.z, e, acc[6]);  acc[7]  = fmaf(a1.w, e, acc[7]);
            acc[8]  = fmaf(a2.x, e, acc[8]);  acc[9]  = fmaf(a2.y, e, acc[9]);
            acc[10] = fmaf(a2.z, e, acc[10]); acc[11] = fmaf(a2.w, e, acc[11]);
            acc[12] = fmaf(a3.x, e, acc[12]); acc[13] = fmaf(a3.y, e, acc[13]);
            acc[14] = fmaf(a3.z, e, acc[14]); acc[15] = fmaf(a3.w, e, acc[15]);
            acc[16] = fmaf(a16, e, acc[16]);  acc[17] = fmaf(a17, e, acc[17]);
            acc[18] = fmaf(a18, e, acc[18]);
        }
#pragma unroll
        for (int k = 0; k < NCLS; k++) acc[k] += __shfl_xor(acc[k], 32);
        const int wv = tid >> 6;
        if ((tid & 63) < 32) {
#pragma unroll
            for (int k = 0; k < NCLS; k++) lds[L_RED + wv * 608 + k * 32 + c] = acc[k];
        }
        __syncthreads();
        float* Ps = P_sum + (size_t)(n * NTILE + tile) * 608;
        for (int i = tid; i < 608; i += 256)
            Ps[i] = lds[L_RED + i] + lds[L_RED + 608 + i]
                  + lds[L_RED + 1216 + i] + lds[L_RED + 1824 + i];
        if (tid < NCLS)
            P_cnt[((size_t)n * NCLS + tid) * NTILE + tile] = lds[L_CNT + tid];
    } else {
        // ================ quad role: S2 partial, one row x 16 channels ======
        const int qb = bid - bid / 3 - 1;        // 0..255
        const int by = qb >> 1;                  // low-res row
        const int ch0 = (qb & 1) * 16 + (tid >> 7) * 8;  // 8 channels/thread
        const int bx = tid & 127;
        const int wv = tid >> 6;
        if ((tid & 63) < ASTR) lds[wv * ASTR + (tid & 63)] = 0.f;
        __syncthreads();

        const float* En = E + (size_t)n * CCH * HWQ;
        const int r0 = (by == 0) ? 0 : by - 1;
        const int r2 = (by == LH - 1) ? LH - 1 : by + 1;
        const int c0 = (bx == 0) ? 0 : bx - 1;
        const int c2 = (bx == LW - 1) ? LW - 1 : bx + 1;
        const int o0 = r0 * LW, o1 = by * LW, o2 = r2 * LW;

        float d2[16];
#pragma unroll
        for (int i = 0; i < 16; i++) d2[i] = 0.f;

#pragma unroll 2
        for (int c = 0; c < 8; c++) {
            const float* Ep = En + (size_t)(ch0 + c) * HWQ;
            float e00 = Ep[o0 + c0], e01 = Ep[o0 + bx], e02 = Ep[o0 + c2];
            float e10 = Ep[o1 + c0], e11 = Ep[o1 + bx], e12 = Ep[o1 + c2];
            float e20 = Ep[o2 + c0], e21 = Ep[o2 + bx], e22 = Ep[o2 + c2];
            float dy0 = e10 - e00, dy1 = e11 - e01, dy2 = e12 - e02;
            float dz0 = e20 - e10, dz1 = e21 - e11, dz2 = e22 - e12;
            float ry[4][3];
            ry[0][0] = fmaf(0.625f, dy0, e00); ry[0][1] = fmaf(0.625f, dy1, e01); ry[0][2] = fmaf(0.625f, dy2, e02);
            ry[1][0] = fmaf(0.875f, dy0, e00); ry[1][1] = fmaf(0.875f, dy1, e01); ry[1][2] = fmaf(0.875f, dy2, e02);
            ry[2][0] = fmaf(0.125f, dz0, e10); ry[2][1] = fmaf(0.125f, dz1, e11); ry[2][2] = fmaf(0.125f, dz2, e12);
            ry[3][0] = fmaf(0.375f, dz0, e10); ry[3][1] = fmaf(0.375f, dz1, e11); ry[3][2] = fmaf(0.375f, dz2, e12);
#pragma unroll
            for (int r = 0; r < 4; r++) {
                float da = ry[r][1] - ry[r][0], db = ry[r][2] - ry[r][1];
                float v0 = fmaf(0.625f, da, ry[r][0]);
                float v1 = fmaf(0.875f, da, ry[r][0]);
                float v2 = fmaf(0.125f, db, ry[r][1]);
                float v3 = fmaf(0.375f, db, ry[r][1]);
                d2[r * 4 + 0] = fmaf(v0, v0, d2[r * 4 + 0]);
                d2[r * 4 + 1] = fmaf(v1, v1, d2[r * 4 + 1]);
                d2[r * 4 + 2] = fmaf(v2, v2, d2[r * 4 + 2]);
                d2[r * 4 + 3] = fmaf(v3, v3, d2[r * 4 + 3]);
            }
        }
        const int* lp = lab + (size_t)n * HWP + (by * 4) * WW + bx * 4;
        float* accW = &lds[wv * ASTR];
#pragma unroll
        for (int r = 0; r < 4; r++) {
            int4 l4 = *(const int4*)(lp + r * WW);
            atomicAdd(&accW[l4.x], d2[r * 4 + 0]);
            atomicAdd(&accW[l4.y], d2[r * 4 + 1]);
            atomicAdd(&accW[l4.z], d2[r * 4 + 2]);
            atomicAdd(&accW[l4.w], d2[r * 4 + 3]);
        }
        __syncthreads();
        if (tid < NCLS)
            P_S2[((size_t)n * NCLS + tid) * QB2 + qb] =
                lds[tid] + lds[ASTR + tid] + lds[2 * ASTR + tid] + lds[3 * ASTR + tid];
    }
}

// reduce partials; intra = (S2 - 2 m.s + cnt|m|^2)/32/(cnt+1); inter pairwise
__global__ __launch_bounds__(640) void k_final(const float* __restrict__ P_sum,
        const float* __restrict__ P_cnt, const float* __restrict__ P_S2,
        float* __restrict__ out) {
    const int n = blockIdx.x, t = threadIdx.x;
    __shared__ float csum[NCLS * 33];
    __shared__ float m[NCLS * 33];
    __shared__ float cnt[NCLS];
    __shared__ float S2[NCLS];
    __shared__ float sIntra, sNfg, sInter;
    if (t == 0) sInter = 0.f;

    if (t < NCLS * CCH) {
        const int k = t >> 5, c = t & 31;
        const float* p = P_sum + (size_t)n * NTILE * (NCLS * CCH) + t;
        float s = 0.f;
        for (int b = 0; b < NTILE; b++) s += p[b * (NCLS * CCH)];
        csum[k * 33 + c] = s;
        const float* pc = P_cnt + ((size_t)n * NCLS + k) * NTILE;
        float sc = 0.f;
        for (int i = c; i < NTILE; i += 32) sc += pc[i];
        const float* ps = P_S2 + ((size_t)n * NCLS + k) * QB2;
        float s2 = 0.f;
        for (int i = c; i < QB2; i += 32) s2 += ps[i];
#pragma unroll
        for (int mk = 16; mk >= 1; mk >>= 1) {
            sc += __shfl_xor(sc, mk);
            s2 += __shfl_xor(s2, mk);
        }
        if (c == 0) { cnt[k] = sc; S2[k] = s2; }
    }
    __syncthreads();
    if (t < NCLS * CCH) {
        const int k = t >> 5, c = t & 31;
        m[k * 33 + c] = csum[k * 33 + c] / (cnt[k] + 1.f);
    }
    __syncthreads();

    // intra + n_fg (threads 1..18 live in wave 0)
    float vi = 0.f, fg = 0.f;
    if (t >= 1 && t < NCLS && cnt[t] > 0.f) {
        fg = 1.f;
        float dot = 0.f, mm = 0.f;
#pragma unroll
        for (int c = 0; c < CCH; c++) {
            float mv = m[t * 33 + c];
            dot = fmaf(mv, csum[t * 33 + c], dot);
            mm = fmaf(mv, mv, mm);
        }
        vi = (S2[t] - 2.f * dot + cnt[t] * mm) * (1.f / 32.f) / (cnt[t] + 1.f);
    }
#pragma unroll
    for (int s_ = 32; s_ >= 1; s_ >>= 1) { vi += __shfl_xor(vi, s_); fg += __shfl_xor(fg, s_); }
    if (t == 0) { sIntra = vi; sNfg = fg; }

    // inter: 18x18 foreground pairs
    float ve = 0.f;
    if (t < 324) {
        int j = 1 + t / 18, k = 1 + t % 18;
        if (cnt[j] > 0.f && cnt[k] > 0.f) {
            float s = 0.f;
#pragma unroll
            for (int c = 0; c < CCH; c++) {
                float d = m[j * 33 + c] - m[k * 33 + c];
                s = fmaf(d, d, s);
            }
            ve = s * (1.f / 32.f);
        }
    }
#pragma unroll
    for (int s_ = 32; s_ >= 1; s_ >>= 1) ve += __shfl_xor(ve, s_);
    if ((t & 63) == 0) atomicAdd(&sInter, ve);
    __syncthreads();
    if (t == 0) out[n] = sIntra / sNfg - sInter / (sNfg * sNfg);
}

extern "C" void kernel_launch(void* const* d_in, const int* in_sizes, int n_in,
                              void* d_out, int out_size, void* d_ws, size_t ws_size,
                              hipStream_t stream) {
    const float* E = (const float*)d_in[0];   // (4,32,128,128) fp32
    const int* lab = (const int*)d_in[1];     // (4,512,512) int
    float* out = (float*)d_out;               // (4,) fp32

    float* ws = (float*)d_ws;
    float* P_sum = ws;                                          // 4*128*608
    float* P_cnt = P_sum + (size_t)NIMG * NTILE * NCLS * CCH;   // 4*19*128
    float* P_S2  = P_cnt + (size_t)NIMG * NCLS * NTILE;         // 4*19*256
    // every partial slot fully overwritten each call -> no memset

    k_main <<<dim3(NTILE + QB2, NIMG), dim3(256), 0, stream>>>(E, lab, P_sum, P_cnt, P_S2);
    k_final<<<dim3(NIMG), dim3(640), 0, stream>>>(P_sum, P_cnt, P_S2, out);
}